// Round 7
// baseline (313.746 us; speedup 1.0000x reference)
//
#include <hip/hip_runtime.h>

#define D_MODEL 1024
#define N_HEADS 16
#define DK 64
#define BATCH 4
#define SEQ 2048
#define MROWS (BATCH * SEQ)   // 8192

typedef float f32x4 __attribute__((ext_vector_type(4)));
typedef short bf16x8 __attribute__((ext_vector_type(8)));
typedef unsigned short u16;
typedef unsigned short u16x8 __attribute__((ext_vector_type(8)));

__device__ __forceinline__ float bf2f(u16 u) {
    union { unsigned int i; float f; } v; v.i = ((unsigned int)u) << 16; return v.f;
}
__device__ __forceinline__ u16 f2bf(float f) {
    union { float f; unsigned int i; } v; v.f = f;
    unsigned int u = v.i;
    u += 0x7fffu + ((u >> 16) & 1u);  // RNE
    return (u16)(u >> 16);
}
// pack two fp32 -> two bf16 (round-half-up) in ONE v_perm: low u16 = a, high = b
__device__ __forceinline__ unsigned int pk2(float a, float b) {
    union { float f; unsigned int i; } ua, ub; ua.f = a; ub.f = b;
    return __builtin_amdgcn_perm(ub.i + 0x8000u, ua.i + 0x8000u, 0x07060302u);
}

// async global->LDS, 16B per lane; LDS dest = wave-uniform base + lane*16
typedef unsigned int u32_as1 __attribute__((address_space(1)));
typedef unsigned int u32_as3 __attribute__((address_space(3)));
__device__ __forceinline__ void gload16(const u16* g, u16* l) {
    __builtin_amdgcn_global_load_lds((const u32_as1*)g, (u32_as3*)l, 16, 0, 0);
}

// ---------------- fused fp32 -> bf16 conversion (all 7 tensors, 8 elems/thread) ----
__global__ __launch_bounds__(256) void convert_all(
    const float* __restrict__ x, const float* __restrict__ pe,
    const float* __restrict__ w0, const float* __restrict__ w1, const float* __restrict__ w2,
    const float* __restrict__ w3, const float* __restrict__ w4,
    u16* __restrict__ xb, u16* __restrict__ pb,
    u16* __restrict__ wb0, u16* __restrict__ wb1, u16* __restrict__ wb2,
    u16* __restrict__ wb3, u16* __restrict__ wb4)
{
    int t = blockIdx.x * 256 + threadIdx.x;   // unit = 8 elems
    const float* src; u16* dst; int idx;
    if (t < 1048576)      { src = x;  dst = xb; idx = t; }
    else if (t < 1310720) { src = pe; dst = pb; idx = t - 1048576; }
    else {
        int r = t - 1310720; int w = r >> 17; idx = r & 131071;
        if      (w == 0) { src = w0; dst = wb0; }
        else if (w == 1) { src = w1; dst = wb1; }
        else if (w == 2) { src = w2; dst = wb2; }
        else if (w == 3) { src = w3; dst = wb3; }
        else             { src = w4; dst = wb4; }
    }
    const float4* p = (const float4*)src + (size_t)idx * 2;
    float4 a = p[0], b = p[1];
    u16x8 o;
    o[0] = f2bf(a.x); o[1] = f2bf(a.y); o[2] = f2bf(a.z); o[3] = f2bf(a.w);
    o[4] = f2bf(b.x); o[5] = f2bf(b.y); o[6] = f2bf(b.z); o[7] = f2bf(b.w);
    *((u16x8*)dst + idx) = o;
}

// ---------------- fused QKVP GEMM: dbuf LDS + prefetch-1, XCD-aware grid ----------
// grid (64, 26), x = row-block (same x-rows => same dispatch%8 => same XCD L2).
// by<24: chunk = by>>3 (0=Q,1=K,2=V), n0 = (by&7)*128, m0 = bx*128.
// by>=24: chunk 3 = P (pe@Wp^T): idx = (by-24)*64+bx, m0 = (idx&15)*128, n0 = ((idx>>4)&7)*128.
// K-loop: single barrier per tile; DMA for tile k+1 issued into the other LDS buffer
// right after the barrier, compute tile k meanwhile -> exposed latency ~ max(0, lat-compute).
__global__ __launch_bounds__(256) void qkv_gemm(
    const u16* __restrict__ xb, const u16* __restrict__ peb,
    const u16* __restrict__ wqb, const u16* __restrict__ wkb,
    const u16* __restrict__ wvb, const u16* __restrict__ wpb,
    const float* __restrict__ bq, const float* __restrict__ bk,
    const float* __restrict__ bv, const float* __restrict__ bp,
    u16* __restrict__ Qb, u16* __restrict__ Kb, u16* __restrict__ V3,
    u16* __restrict__ Pb)
{
    __shared__ __align__(16) u16 As[2][128 * 32];
    __shared__ __align__(16) u16 Bs[2][128 * 32];

    const int tid  = threadIdx.x;
    const int lane = tid & 63;
    const int wv   = tid >> 6;
    const int l15  = lane & 15;
    const int quad = lane >> 4;
    int chunk, m0, n0;
    if (blockIdx.y < 24) {
        chunk = blockIdx.y >> 3; n0 = (blockIdx.y & 7) * 128; m0 = blockIdx.x * 128;
    } else {
        chunk = 3;
        int idx = (blockIdx.y - 24) * 64 + blockIdx.x;
        m0 = (idx & 15) * 128; n0 = ((idx >> 4) & 7) * 128;
    }
    const int wrow = (wv >> 1) * 64;
    const int wcol = (wv & 1) * 64;

    f32x4 acc[4][4];
#pragma unroll
    for (int i = 0; i < 4; ++i)
#pragma unroll
        for (int j = 0; j < 4; ++j) acc[i][j] = f32x4{0.f, 0.f, 0.f, 0.f};

    const int lr = lane >> 2;
    const int lc = (lane & 3) * 8;
    const u16* Abase = (chunk == 3) ? peb : xb;
    const u16* Wbase = (chunk == 0) ? wqb : ((chunk == 1) ? wkb : ((chunk == 2) ? wvb : wpb));
    const u16* Ag = Abase + (size_t)(m0 + wv * 16 + lr) * 1024 + lc;
    const u16* Wg = Wbase + (size_t)(n0 + wv * 16 + lr) * 1024 + lc;
    const int woff = wv * 16 * 32;

    auto stage = [&](int k, int buf) {
        gload16(Ag + k, &As[buf][woff]);
        gload16(Ag + (size_t)64 * 1024 + k, &As[buf][woff + 64 * 32]);
        gload16(Wg + k, &Bs[buf][woff]);
        gload16(Wg + (size_t)64 * 1024 + k, &Bs[buf][woff + 64 * 32]);
    };
    auto compute = [&](int buf) {
        bf16x8 af[4], bfr[4];
#pragma unroll
        for (int i = 0; i < 4; ++i)
            af[i] = *(const bf16x8*)&As[buf][(wrow + 16 * i + l15) * 32 + quad * 8];
#pragma unroll
        for (int j = 0; j < 4; ++j)
            bfr[j] = *(const bf16x8*)&Bs[buf][(wcol + 16 * j + l15) * 32 + quad * 8];
#pragma unroll
        for (int i = 0; i < 4; ++i)
#pragma unroll
            for (int j = 0; j < 4; ++j)
                acc[i][j] = __builtin_amdgcn_mfma_f32_16x16x32_bf16(af[i], bfr[j], acc[i][j], 0, 0, 0);
    };

    stage(0, 0);
    for (int k0 = 0; k0 < 1024; k0 += 64) {
        __syncthreads();                 // drains tile-k0 DMA; all waves done reading buf1
        stage(k0 + 32, 1);               // k0+32 <= 992 < 1024 always
        compute(0);
        __syncthreads();                 // drains tile-(k0+32) DMA; all done reading buf0
        if (k0 + 64 < 1024) stage(k0 + 64, 0);
        compute(1);
    }

    // epilogue: C row=(lane>>4)*4+r, col=lane&15  [m89 layout]
    const int r0 = quad * 4;
    const float* bias = (chunk == 0) ? bq : ((chunk == 1) ? bk : ((chunk == 2) ? bv : bp));
    u16* dst = (chunk == 0) ? Qb : ((chunk == 1) ? Kb : Pb);   // chunk 2 handled below
#pragma unroll
    for (int i = 0; i < 4; ++i) {
#pragma unroll
        for (int j = 0; j < 4; ++j) {
            int col = n0 + wcol + 16 * j + l15;
            int row0 = m0 + wrow + 16 * i + r0;      // 4 consecutive rows
            float bvv = bias[col];
            if (chunk == 2) {                        // V -> interleaved layout
                int hh = col >> 6, d = col & 63;
                int bb = row0 >> 11, sl = row0 & 2047;
                union { u16 h[4]; uint2 v; } pk;
#pragma unroll
                for (int r = 0; r < 4; ++r) pk.h[r] = f2bf(acc[i][j][r] + bvv);
                *((uint2*)V3 + ((size_t)(bb * 16 + hh) * 512 + (sl >> 2)) * 64 + d) = pk.v;
            } else {                                 // Q / K / P row-major bf16
#pragma unroll
                for (int r = 0; r < 4; ++r)
                    dst[(size_t)(row0 + r) * 1024 + col] = f2bf(acc[i][j][r] + bvv);
            }
        }
    }
}

// ---------------- output GEMM: out = AO @ Wo^T + bo (fp32), dbuf K-loop ----------------
// grid (64, 8): x = row-block => same-A-tile sharers on one XCD.
__global__ __launch_bounds__(256) void gemm_out(
    const u16* __restrict__ A, const u16* __restrict__ W,
    const float* __restrict__ bias, float* __restrict__ Cout)
{
    __shared__ __align__(16) u16 As[2][128 * 32];
    __shared__ __align__(16) u16 Bs[2][128 * 32];

    const int tid  = threadIdx.x;
    const int lane = tid & 63;
    const int wv   = tid >> 6;
    const int l15  = lane & 15;
    const int quad = lane >> 4;
    const int m0   = blockIdx.x * 128;
    const int n0   = blockIdx.y * 128;
    const int wrow = (wv >> 1) * 64;
    const int wcol = (wv & 1) * 64;

    f32x4 acc[4][4];
#pragma unroll
    for (int i = 0; i < 4; ++i)
#pragma unroll
        for (int j = 0; j < 4; ++j) acc[i][j] = f32x4{0.f, 0.f, 0.f, 0.f};

    const int lr = lane >> 2;
    const int lc = (lane & 3) * 8;
    const u16* Ag = A + (size_t)(m0 + wv * 16 + lr) * 1024 + lc;
    const u16* Wg = W + (size_t)(n0 + wv * 16 + lr) * 1024 + lc;
    const int woff = wv * 16 * 32;

    auto stage = [&](int k, int buf) {
        gload16(Ag + k, &As[buf][woff]);
        gload16(Ag + (size_t)64 * 1024 + k, &As[buf][woff + 64 * 32]);
        gload16(Wg + k, &Bs[buf][woff]);
        gload16(Wg + (size_t)64 * 1024 + k, &Bs[buf][woff + 64 * 32]);
    };
    auto compute = [&](int buf) {
        bf16x8 af[4], bfr[4];
#pragma unroll
        for (int i = 0; i < 4; ++i)
            af[i] = *(const bf16x8*)&As[buf][(wrow + 16 * i + l15) * 32 + quad * 8];
#pragma unroll
        for (int j = 0; j < 4; ++j)
            bfr[j] = *(const bf16x8*)&Bs[buf][(wcol + 16 * j + l15) * 32 + quad * 8];
#pragma unroll
        for (int i = 0; i < 4; ++i)
#pragma unroll
            for (int j = 0; j < 4; ++j)
                acc[i][j] = __builtin_amdgcn_mfma_f32_16x16x32_bf16(af[i], bfr[j], acc[i][j], 0, 0, 0);
    };

    stage(0, 0);
    for (int k0 = 0; k0 < 1024; k0 += 64) {
        __syncthreads();
        stage(k0 + 32, 1);
        compute(0);
        __syncthreads();
        if (k0 + 64 < 1024) stage(k0 + 64, 0);
        compute(1);
    }

    const int r0 = quad * 4;
#pragma unroll
    for (int i = 0; i < 4; ++i)
#pragma unroll
        for (int j = 0; j < 4; ++j) {
            int col = n0 + wcol + 16 * j + l15;
            float bvv = bias[col];
#pragma unroll
            for (int r = 0; r < 4; ++r) {
                int row = m0 + wrow + 16 * i + r0 + r;
                Cout[(size_t)row * 1024 + col] = acc[i][j][r] + bvv;
            }
        }
}

// ---------------- MFMA causal flash attention: folded, pipelined, no-max softmax ----
// grid (64, 8): x = b*16+h (K/V sharers of one (b,h) land on one XCD), y = j.
// 512 thr = 8 waves; waves 0-3 own q-tile j, waves 4-7 own q-tile 15-j.
// Prologue builds qf = (Q + P[s]) * 0.125*log2e (P shared across batch).
// Fixed-max exp2 softmax (scores bounded): no max tracking, no O rescale;
// l reduced across quads only in the epilogue. Probs packed to bf16 via v_perm.
__global__ __launch_bounds__(512, 4) void flash_attn_mfma(
    const u16* __restrict__ Q, const u16* __restrict__ Kq,
    const u16* __restrict__ V3, const u16* __restrict__ Pb, u16* __restrict__ O)
{
    __shared__ __align__(16) u16 Ks[64 * 72];        // [key][d]
    __shared__ __align__(16) u16 Vs[64 * 72];        // [d][key]
    __shared__ __align__(16) u16 Ps[8][32 * 72];     // per-wave softmax P [q][key]

    const int tid  = threadIdx.x;
    const int lane = tid & 63;
    const int wv   = tid >> 6;
    const int l15  = lane & 15;
    const int quad = lane >> 4;
    const int j    = blockIdx.y;            // 0..7
    const int h    = blockIdx.x & 15;
    const int b    = blockIdx.x >> 4;
    const int qblk = (wv < 4) ? j : (15 - j);
    const int wq0  = qblk * 128 + (wv & 3) * 32;

    // Q B-frags: (Q + P[s]) * 0.125*log2e, built once per block
    bf16x8 qf[2][2];
    const size_t qrowbase = (size_t)(b * SEQ) * D_MODEL + h * DK;
#pragma unroll
    for (int qb = 0; qb < 2; ++qb)
#pragma unroll
        for (int ks = 0; ks < 2; ++ks) {
            int qrow = wq0 + qb * 16 + l15;
            u16x8 qr = *(const u16x8*)(Q + qrowbase + (size_t)qrow * D_MODEL + ks * 32 + quad * 8);
            u16x8 pr = *(const u16x8*)(Pb + (size_t)qrow * D_MODEL + h * DK + ks * 32 + quad * 8);
            u16x8 o;
#pragma unroll
            for (int t = 0; t < 8; ++t)
                o[t] = f2bf((bf2f(qr[t]) + bf2f(pr[t])) * 0.180336880111120f);  // 0.125*log2e
            qf[qb][ks] = *(bf16x8*)&o;
        }

    f32x4 Oacc[2][4];
#pragma unroll
    for (int i = 0; i < 2; ++i)
#pragma unroll
        for (int jj = 0; jj < 4; ++jj) Oacc[i][jj] = f32x4{0.f, 0.f, 0.f, 0.f};
    float l_r[2] = {0.f, 0.f};

    // staging: 512 threads cover one 64x64 tile of K and V (1 u16x8 chunk each)
    const int sr  = tid >> 3;
    const int sc8 = (tid & 7) * 8;
    const u16* Kg = Kq + (size_t)(b * SEQ + sr) * D_MODEL + h * DK + sc8;
    // V interleaved: uint2 index = ((b*16+h)*512 + sgrp)*64 + d ; sgrp = kt*16 + (tid&7)*2
    const uint2* Vg = (const uint2*)V3 + ((size_t)(b * 16 + h) * 512 + (tid & 7) * 2) * 64 + sr;
    u16x8 kreg = *(const u16x8*)Kg;
    uint2 v0 = Vg[0], v1 = Vg[64];

    const int ktmaxb = 31 - 2 * j;   // union of both halves' causal ranges
    for (int kt = 0; kt <= ktmaxb; ++kt) {
        __syncthreads();
        *(u16x8*)&Ks[sr * 72 + sc8] = kreg;
        *(uint2*)&Vs[sr * 72 + sc8] = v0;
        *(uint2*)&Vs[sr * 72 + sc8 + 4] = v1;
        __syncthreads();
        if (kt < ktmaxb) {    // prefetch next tile (hidden under compute)
            kreg = *(const u16x8*)(Kg + (size_t)(kt + 1) * 64 * D_MODEL);
            v0 = Vg[(size_t)(kt + 1) * 1024];
            v1 = Vg[(size_t)(kt + 1) * 1024 + 64];
        }
        if (kt * 64 > wq0 + 31) continue;   // tile fully masked for this wave

        // S^T = K-tile @ Q^T : C[key=16kb+4quad+r][q=16qb+l15]
        f32x4 sacc[4][2];
#pragma unroll
        for (int kb = 0; kb < 4; ++kb)
#pragma unroll
            for (int qb = 0; qb < 2; ++qb) sacc[kb][qb] = f32x4{0.f, 0.f, 0.f, 0.f};
#pragma unroll
        for (int ks = 0; ks < 2; ++ks) {
            bf16x8 kf[4];
#pragma unroll
            for (int kb = 0; kb < 4; ++kb)
                kf[kb] = *(const bf16x8*)&Ks[(kb * 16 + l15) * 72 + ks * 32 + quad * 8];
#pragma unroll
            for (int kb = 0; kb < 4; ++kb)
#pragma unroll
                for (int qb = 0; qb < 2; ++qb)
                    sacc[kb][qb] = __builtin_amdgcn_mfma_f32_16x16x32_bf16(kf[kb], qf[qb][ks], sacc[kb][qb], 0, 0, 0);
        }

        if (kt * 64 + 63 > wq0) {   // diagonal: causal mask
#pragma unroll
            for (int kb = 0; kb < 4; ++kb) {
                int key_g = kt * 64 + kb * 16 + quad * 4;
#pragma unroll
                for (int qb = 0; qb < 2; ++qb) {
                    int q_g = wq0 + qb * 16 + l15;
#pragma unroll
                    for (int r = 0; r < 4; ++r)
                        if (key_g + r > q_g) sacc[kb][qb][r] = -1e30f;
                }
            }
        }

        // fixed-max softmax: p = exp2(s); accumulate per-lane l; pack P via v_perm
        u16* Pw = Ps[wv];
#pragma unroll
        for (int qb = 0; qb < 2; ++qb) {
            float s = 0.f;
#pragma unroll
            for (int kb = 0; kb < 4; ++kb) {
                float p0 = __builtin_amdgcn_exp2f(sacc[kb][qb][0]);
                float p1 = __builtin_amdgcn_exp2f(sacc[kb][qb][1]);
                float p2 = __builtin_amdgcn_exp2f(sacc[kb][qb][2]);
                float p3 = __builtin_amdgcn_exp2f(sacc[kb][qb][3]);
                s += (p0 + p1) + (p2 + p3);
                uint2 pk; pk.x = pk2(p0, p1); pk.y = pk2(p2, p3);
                *(uint2*)&Pw[(qb * 16 + l15) * 72 + kb * 16 + quad * 4] = pk;
            }
            l_r[qb] += s;
        }

        // PV: O[q 32][d 64] += P @ V  (no rescale needed)
#pragma unroll
        for (int ks = 0; ks < 2; ++ks) {
            bf16x8 pf[2], vf[4];
#pragma unroll
            for (int qb = 0; qb < 2; ++qb)
                pf[qb] = *(const bf16x8*)&Pw[(qb * 16 + l15) * 72 + ks * 32 + quad * 8];
#pragma unroll
            for (int db = 0; db < 4; ++db)
                vf[db] = *(const bf16x8*)&Vs[(db * 16 + l15) * 72 + ks * 32 + quad * 8];
#pragma unroll
            for (int qb = 0; qb < 2; ++qb)
#pragma unroll
                for (int db = 0; db < 4; ++db)
                    Oacc[qb][db] = __builtin_amdgcn_mfma_f32_16x16x32_bf16(pf[qb], vf[db], Oacc[qb][db], 0, 0, 0);
        }
    }

    // epilogue: reduce l across quads, normalize, store (C-frag rows q=quad*4+r)
    float linv[2];
#pragma unroll
    for (int qb = 0; qb < 2; ++qb) {
        float s = l_r[qb];
        s += __shfl_xor(s, 16);
        s += __shfl_xor(s, 32);
        linv[qb] = 1.f / s;
    }
#pragma unroll
    for (int qb = 0; qb < 2; ++qb)
#pragma unroll
        for (int r = 0; r < 4; ++r) {
            float li = __shfl(linv[qb], quad * 4 + r);
            size_t row = (size_t)(b * SEQ + wq0 + qb * 16 + quad * 4 + r) * D_MODEL + h * DK;
#pragma unroll
            for (int db = 0; db < 4; ++db)
                O[row + db * 16 + l15] = f2bf(Oacc[qb][db][r] * li);
        }
}

// ---------------------------------------------------------------------------
extern "C" void kernel_launch(void* const* d_in, const int* in_sizes, int n_in,
                              void* d_out, int out_size, void* d_ws, size_t ws_size,
                              hipStream_t stream) {
    const float* x  = (const float*)d_in[0];
    const float* pe = (const float*)d_in[1];
    const float* Wq = (const float*)d_in[2];  const float* bq = (const float*)d_in[3];
    const float* Wk = (const float*)d_in[4];  const float* bk = (const float*)d_in[5];
    const float* Wv = (const float*)d_in[6];  const float* bv = (const float*)d_in[7];
    const float* Wp = (const float*)d_in[8];  const float* bp = (const float*)d_in[9];
    const float* Wo = (const float*)d_in[10]; const float* bo = (const float*)d_in[11];
    float* out = (float*)d_out;
    char* ws = (char*)d_ws;

    size_t off = 0;
    u16* xb  = (u16*)(ws + off); off += (size_t)MROWS * D_MODEL * 2;   // reused as AO
    u16* peb = (u16*)(ws + off); off += (size_t)SEQ * D_MODEL * 2;
    u16* wqb = (u16*)(ws + off); off += (size_t)D_MODEL * D_MODEL * 2;
    u16* wkb = (u16*)(ws + off); off += (size_t)D_MODEL * D_MODEL * 2;
    u16* wvb = (u16*)(ws + off); off += (size_t)D_MODEL * D_MODEL * 2;
    u16* wpb = (u16*)(ws + off); off += (size_t)D_MODEL * D_MODEL * 2;
    u16* wob = (u16*)(ws + off); off += (size_t)D_MODEL * D_MODEL * 2;
    u16* Qb  = (u16*)(ws + off); off += (size_t)MROWS * D_MODEL * 2;
    u16* Kb  = (u16*)(ws + off); off += (size_t)MROWS * D_MODEL * 2;
    u16* V3b = (u16*)(ws + off); off += (size_t)MROWS * D_MODEL * 2;   // interleaved V
    u16* Pb  = (u16*)(ws + off); off += (size_t)SEQ * D_MODEL * 2;     // pos projection
    u16* AO = xb;             // attention output aliases xb (x consumed by qkv_gemm)

    convert_all<<<7680, 256, 0, stream>>>(x, pe, Wq, Wk, Wv, Wp, Wo,
                                          xb, peb, wqb, wkb, wvb, wpb, wob);

    // Q / K / V / P, uniform K=1024, XCD-aware grid, double-buffered K-loop
    qkv_gemm<<<dim3(64, 26), 256, 0, stream>>>(
        xb, peb, wqb, wkb, wvb, wpb, bq, bk, bv, bp, Qb, Kb, V3b, Pb);

    flash_attn_mfma<<<dim3(64, 8), 512, 0, stream>>>(Qb, Kb, V3b, Pb, AO);

    // out = AO @ Wo^T + bo  (fp32)
    gemm_out<<<dim3(64, 8), 256, 0, stream>>>(AO, wob, bo, out);
}